// Round 9
// baseline (115.687 us; speedup 1.0000x reference)
//
#include <hip/hip_runtime.h>
#include <hip/hip_bf16.h>
#include <math.h>
#include <string.h>

#define Bn 8
#define Cn 128
#define Nn 4096   // H*W
#define Mn 1024   // N/4
#define C8n 16
#define C2n 64

typedef __attribute__((ext_vector_type(8))) short short8;            // 8 bf16 = 4 VGPRs
typedef __attribute__((ext_vector_type(4))) float floatx4;           // MFMA C/D
typedef __attribute__((ext_vector_type(4))) unsigned short ushortx4; // b64 pack

typedef const __attribute__((address_space(1))) void gv_t;           // global
typedef __attribute__((address_space(3))) void lv_t;                 // LDS

__device__ __forceinline__ unsigned short f2bf(float f) {
    union { float f; unsigned u; } v; v.f = f;
    unsigned r = v.u + 0x7fff + ((v.u >> 16) & 1);   // RNE
    return (unsigned short)(r >> 16);
}
// packed 2xf32 -> 2xbf16 (v_cvt_pk_bf16_f32 on gfx950)
__device__ __forceinline__ unsigned pk2(float a, float b) {
    __hip_bfloat162 h = __float22bfloat162_rn(make_float2(a, b));
    union { __hip_bfloat162 h2; unsigned u; } cv;
    cv.h2 = h;
    return cv.u;
}

// ---------------------------------------------------------------------------
// K1 (MFMA): unchanged from round 8 (proven correct). Outputs:
//  thA[b][nt 256][qd 2][nl 16][dj 8]   (theta * log2e, A-frag order)
//  phB[b][mt 64][qd 2][ml 16][dj 8]    (phi, B-frag order)
//  gB [b][h2 32][cs 4][sq 4][cl 16][sj 8]  (g, B-frag, m permuted s=((m&15)<<1)|(m>>4))
// ---------------------------------------------------------------------------
__global__ __launch_bounds__(256) void k1_pre(
    const float* __restrict__ x,
    const float* __restrict__ w_theta, const float* __restrict__ b_theta,
    const float* __restrict__ w_phi,   const float* __restrict__ b_phi,
    const float* __restrict__ w_g,     const float* __restrict__ b_g,
    unsigned short* __restrict__ thA,
    unsigned short* __restrict__ phB,
    unsigned short* __restrict__ gB)
{
    __shared__ unsigned short wA[6 * 4 * 64 * 8];   // 24 KB [ot][kc][lane][j]
    __shared__ unsigned short xB[8 * 4 * 64 * 8];   // 32 KB [pt][kc][lane][j]
    __shared__ unsigned short pool[80][33];         // 5.2 KB phi rows 0-15, g 16-79
    __shared__ float biases[96];                    // th*L2E 0-15, phi 16-31, g 32-95

    const int t    = threadIdx.x;
    const int b    = blockIdx.x & 7;
    const int h2   = blockIdx.x >> 3;
    const int wv   = t >> 6;
    const int lane = t & 63;
    const int q    = lane >> 4;
    const int l15  = lane & 15;
    const float L2E = 1.4426950408889634f;

    if (t < 96)
        biases[t] = (t < 16) ? b_theta[t] * L2E
                  : (t < 32) ? b_phi[t - 16] : b_g[t - 32];

    #pragma unroll
    for (int k = 0; k < 12; ++k) {
        int u  = t + k * 256;
        int oc = u >> 5, c4 = u & 31;
        const float* src = (oc < 16) ? (w_theta + oc * Cn)
                         : (oc < 32) ? (w_phi + (oc - 16) * Cn)
                                     : (w_g + (oc - 32) * Cn);
        float4 wv4 = *(const float4*)(src + c4 * 4);
        float sc = (oc < 16) ? L2E : 1.f;
        int c = c4 * 4;
        int ot = oc >> 4, kc = c >> 5, qq = (c >> 3) & 3, jj = c & 7;  // jj in {0,4}
        uint2 pk = { pk2(wv4.x * sc, wv4.y * sc), pk2(wv4.z * sc, wv4.w * sc) };
        *(uint2*)(wA + (((ot * 4 + kc) * 64 + qq * 16 + (oc & 15)) * 8 + jj)) = pk;
    }

    const float* xb = x + (size_t)b * Cn * Nn + h2 * 128;
    #pragma unroll
    for (int k = 0; k < 16; ++k) {
        int u   = t + k * 256;
        int pos = u & 127, c4 = u >> 7;
        int c   = c4 * 4;
        float v0 = xb[(size_t)(c + 0) * Nn + pos];
        float v1 = xb[(size_t)(c + 1) * Nn + pos];
        float v2 = xb[(size_t)(c + 2) * Nn + pos];
        float v3 = xb[(size_t)(c + 3) * Nn + pos];
        int pt = pos >> 4, kc = c >> 5, qq = (c >> 3) & 3, jj = c & 7;
        uint2 pk = { pk2(v0, v1), pk2(v2, v3) };
        *(uint2*)(xB + (((pt * 4 + kc) * 64 + qq * 16 + (pos & 15)) * 8 + jj)) = pk;
    }
    __syncthreads();

    floatx4 acc[6][2];
    #pragma unroll
    for (int ot = 0; ot < 6; ++ot)
        #pragma unroll
        for (int p2 = 0; p2 < 2; ++p2) acc[ot][p2] = (floatx4){0.f, 0.f, 0.f, 0.f};

    #pragma unroll
    for (int kc = 0; kc < 4; ++kc) {
        short8 Bf0 = *(const short8*)(xB + ((wv * 4 + kc) * 64 + lane) * 8);
        short8 Bf1 = *(const short8*)(xB + (((wv + 4) * 4 + kc) * 64 + lane) * 8);
        #pragma unroll
        for (int ot = 0; ot < 6; ++ot) {
            short8 Af = *(const short8*)(wA + ((ot * 4 + kc) * 64 + lane) * 8);
            acc[ot][0] = __builtin_amdgcn_mfma_f32_16x16x32_bf16(Af, Bf0, acc[ot][0], 0, 0, 0);
            acc[ot][1] = __builtin_amdgcn_mfma_f32_16x16x32_bf16(Af, Bf1, acc[ot][1], 0, 0, 0);
        }
    }

    #pragma unroll
    for (int p2 = 0; p2 < 2; ++p2) {
        const int pt = wv + p2 * 4;
        float v0 = acc[0][p2][0] + biases[q * 4 + 0];
        float v1 = acc[0][p2][1] + biases[q * 4 + 1];
        float v2 = acc[0][p2][2] + biases[q * 4 + 2];
        float v3 = acc[0][p2][3] + biases[q * 4 + 3];
        uint2 pk = { pk2(v0, v1), pk2(v2, v3) };
        *(uint2*)(thA + ((((size_t)b * 256 + h2 * 8 + pt) * 2 + (q >> 1)) * 128
                         + l15 * 8 + (q & 1) * 4)) = pk;
    }

    #pragma unroll
    for (int ot = 1; ot < 6; ++ot) {
        #pragma unroll
        for (int r = 0; r < 4; ++r) {
            float vmax = fmaxf(acc[ot][0][r], acc[ot][1][r]);
            float pmax = fmaxf(vmax, __shfl_xor(vmax, 1, 64));
            if ((l15 & 1) == 0) {
                int oc = (ot - 1) * 16 + q * 4 + r;      // 0..79
                int w2 = wv * 8 + (l15 >> 1);            // 0..31
                pool[oc][w2] = f2bf(pmax + biases[16 + oc]);
            }
        }
    }
    __syncthreads();

    if (t < 64) {        // phi: units (w2h 2, ml 16, dh 2)
        int w2h = t >> 5, ml = (t >> 1) & 15, dh = t & 1;
        int w2 = w2h * 16 + ml;
        ushortx4 lo, hi;
        #pragma unroll
        for (int j = 0; j < 4; ++j) { lo[j] = pool[dh * 8 + j][w2];
                                      hi[j] = pool[dh * 8 + 4 + j][w2]; }
        unsigned short* dst = phB + (((size_t)b * 64 + h2 * 2 + w2h) * 2 + dh) * 128 + ml * 8;
        *(ushortx4*)dst = lo;
        *(ushortx4*)(dst + 4) = hi;
    }
    {                    // g: units (c 64, sq 4): w2 = (j&1)*16 + sq*4 + (j>>1)
        int c = t >> 2, sq = t & 3;
        ushortx4 lo, hi;
        #pragma unroll
        for (int j = 0; j < 8; ++j) {
            int w2 = (j & 1) * 16 + sq * 4 + (j >> 1);
            unsigned short v = pool[16 + c][w2];
            if (j < 4) lo[j] = v; else hi[j - 4] = v;
        }
        unsigned short* dst = gB + ((((size_t)b * 32 + h2) * 4 + (c >> 4)) * 4 + sq) * 128
                              + (c & 15) * 8;
        *(ushortx4*)dst = lo;
        *(ushortx4*)(dst + 4) = hi;
    }
}

// ---------------------------------------------------------------------------
// K2: MFMA attention + final conv + residual.
// Round-9: occupancy doubled via wave-level m-split. Block = 4 waves =
// 2 n-tiles x 2 m-halves; each wave does 16 n x 512 m in 16 chunks of 32 m,
// two double-buffered DMA streams (one per m-half). No online max (round 7)
// -> partial (O, L) merge across the wave pair is a pure add via LDS.
// Grid 1024 -> 4 blocks/CU, 16 waves/CU. LDS 26112 B.
// Layout: staging 4x5120 @0 | P 4x1280 @20480 | battn @25600.
// Post-loop overlays: Opart 2x4352 @0, Lpart @8704 | Obuf 2x2304 @20480 |
// wAe 16384 @0 (after partials are dead).
// ---------------------------------------------------------------------------
__global__ __launch_bounds__(256, 4) void k2_attn(
    const float* __restrict__ x,
    const unsigned short* __restrict__ thA,
    const unsigned short* __restrict__ phB,
    const unsigned short* __restrict__ gB,
    const float* __restrict__ w_attn, const float* __restrict__ b_attn,
    const float* __restrict__ sigma_p,
    float* __restrict__ out)
{
    __shared__ __attribute__((aligned(16))) char smem[26112];
    char*  Pall  = smem + 20480;         // 4 x 1280 B: per-wave P
    float* battn = (float*)(smem + 25600);

    const int tid  = threadIdx.x;
    const int wave = tid >> 6;
    const int lane = tid & 63;
    const int q    = lane >> 4;          // quad 0..3
    const int l15  = lane & 15;
    const int b    = blockIdx.x & 7;     // XCD-local b
    const int nb   = blockIdx.x >> 3;    // 0..127 (32-n block tile)
    const int t    = wave & 1;           // n-tile within block
    const int h    = wave >> 1;          // m-half
    const int ntile = nb * 2 + t;        // global 16-n tile id
    const int nw   = ntile * 16;
    char* Pbase = Pall + wave * 1280;    // [16 n][40 bf16] stride 80 B

    const float sg = sigma_p[0];

    // theta A-frag (quads 2,3 are the K zero-padding)
    short8 thf = {};
    if (q < 2)
        thf = *(const short8*)(thA + ((((size_t)b * 256 + ntile) * 2 + q) * 16 + l15) * 8);

    floatx4 O[4];                        // O[cs] : D[n][c] accumulators
    #pragma unroll
    for (int cs = 0; cs < 4; ++cs) O[cs] = (floatx4){0.f, 0.f, 0.f, 0.f};
    float L[4] = {0.f, 0.f, 0.f, 0.f};

    const char* phb = (const char*)(phB + (size_t)b * 16384);  // 32 KB/b
    const char* gbb = (const char*)(gB  + (size_t)b * 65536);  // 128 KB/b
    const char* sph = phb + h * 16384;   // this half's phi (16 KB)
    const char* sgb = gbb + h * 65536;   // this half's g (64 KB)
    char* mybuf = smem + h * 10240;      // this half's staging (2 x 5120)

    // ---- DMA issue for chunk s into parity buffer (5 x 1KB, split by t) ----
    // chunk s of this half: phi @ s*1024 (1KB), g @ s*4096 (4KB)
    {
        const char* srcp = sph;
        const char* srcg = sgb;
        char* dst = mybuf;               // parity 0
        for (int j = t; j < 5; j += 2) {
            const char* src = (j == 0) ? srcp : (srcg + (j - 1) * 1024);
            __builtin_amdgcn_global_load_lds((gv_t*)(src + lane * 16),
                                             (lv_t*)(dst + j * 1024), 16, 0, 0);
        }
    }

    for (int s = 0; s < 16; ++s) {
        __syncthreads();                 // drains vmcnt -> chunk s DMA complete
        if (s < 15) {                    // DMA for s+1 flies during compute below
            char* dst = mybuf + ((s + 1) & 1) * 5120;
            const char* srcp = sph + (s + 1) * 1024;
            const char* srcg = sgb + (size_t)(s + 1) * 4096;
            for (int j = t; j < 5; j += 2) {
                const char* src = (j == 0) ? srcp : (srcg + (j - 1) * 1024);
                __builtin_amdgcn_global_load_lds((gv_t*)(src + lane * 16),
                                                 (lv_t*)(dst + j * 1024), 16, 0, 0);
            }
        }
        const char* cbuf = mybuf + (s & 1) * 5120;
        const unsigned short* phis = (const unsigned short*)cbuf;          // [mt 2][qd 2][ml 16][dj 8]
        const unsigned short* gs   = (const unsigned short*)(cbuf + 1024); // [cs 4][sq 4][cl 16][sj 8]

        // ---- scores (2 m-tiles) -> exp2 -> P ----
        short8 bf0 = {}, bf1 = {};
        if (q < 2) {
            bf0 = *(const short8*)(phis + ((0 * 2 + q) * 16 + l15) * 8);
            bf1 = *(const short8*)(phis + ((1 * 2 + q) * 16 + l15) * 8);
        }
        floatx4 S0 = __builtin_amdgcn_mfma_f32_16x16x32_bf16(
                         thf, bf0, (floatx4){0.f, 0.f, 0.f, 0.f}, 0, 0, 0);
        floatx4 S1 = __builtin_amdgcn_mfma_f32_16x16x32_bf16(
                         thf, bf1, (floatx4){0.f, 0.f, 0.f, 0.f}, 0, 0, 0);
        #pragma unroll
        for (int r = 0; r < 4; ++r) {
            float pa = exp2f(S0[r]);
            float pb = exp2f(S1[r]);
            L[r] += pa + pb;
            *(unsigned*)(Pbase + (q * 4 + r) * 80 + l15 * 4) = pk2(pa, pb);
        }
        // no barrier: Pbase is wave-private; same-wave DS ops execute in order

        // ---- PV: one 32-m chunk ----
        short8 Af = *(const short8*)(Pbase + l15 * 80 + q * 16);
        #pragma unroll
        for (int cs = 0; cs < 4; ++cs) {
            short8 Bf = *(const short8*)(gs + ((cs * 4 + q) * 16 + l15) * 8);
            O[cs] = __builtin_amdgcn_mfma_f32_16x16x32_bf16(Af, Bf, O[cs], 0, 0, 0);
        }
    }

    // ---- L: sum across the 16 lanes sharing each score row ----
    #pragma unroll
    for (int d = 1; d <= 8; d <<= 1)
        #pragma unroll
        for (int r = 0; r < 4; ++r) L[r] += __shfl_xor(L[r], d, 64);

    // ---- merge m-halves (pure add; no max rescale needed) ----
    __syncthreads();                     // flash loop done everywhere
    float* Lpart = (float*)(smem + 8704);        // 2 x 16 floats
    if (h == 1) {                        // write partials: O fp32 [t][n][c], stride 272 B
        #pragma unroll
        for (int r = 0; r < 4; ++r) {
            float* Orow = (float*)(smem + t * 4352 + (q * 4 + r) * 272);
            #pragma unroll
            for (int cs = 0; cs < 4; ++cs) Orow[cs * 16 + l15] = O[cs][r];
            if (l15 == 0) Lpart[t * 16 + q * 4 + r] = L[r];
        }
    }
    if (tid < 128) battn[tid] = b_attn[tid];
    __syncthreads();                     // partials visible
    unsigned short* Obuf = (unsigned short*)(smem + 20480);  // 2 x 1152 shorts, stride 72
    if (h == 0) {                        // merge + normalize + write Obuf bf16
        #pragma unroll
        for (int r = 0; r < 4; ++r) {
            const float* Orow = (const float*)(smem + t * 4352 + (q * 4 + r) * 272);
            #pragma unroll
            for (int cs = 0; cs < 4; ++cs) O[cs][r] += Orow[cs * 16 + l15];
            L[r] += Lpart[t * 16 + q * 4 + r];
        }
        float inv[4];
        #pragma unroll
        for (int r = 0; r < 4; ++r) inv[r] = 1.0f / L[r];
        unsigned short* Ob = Obuf + t * 1152;
        #pragma unroll
        for (int cs = 0; cs < 4; ++cs)
            #pragma unroll
            for (int r = 0; r < 4; ++r)
                Ob[(q * 4 + r) * 72 + cs * 16 + l15] = f2bf(O[cs][r] * inv[r]);
    }
    __syncthreads();                     // Obuf ready; partials dead

    // ---- stage w_attn A-frags [ot 8][kc 2][ol 16][c&31 32] (16 KB @0) ----
    {
        unsigned short* wAe = (unsigned short*)smem;
        #pragma unroll
        for (int k = 0; k < 8; ++k) {
            int i = tid + k * 256;               // 2048 f4 = 128x64 f32
            float4 wv = ((const float4*)w_attn)[i];
            int o = i >> 4, c = (i & 15) * 4;
            uint2 pk = { pk2(wv.x, wv.y), pk2(wv.z, wv.w) };
            *(uint2*)(wAe + ((o >> 4) * 2 + (c >> 5)) * 512 + (o & 15) * 32 + (c & 31)) = pk;
        }
    }
    __syncthreads();                     // wAe visible

    // ---- epilogue conv + residual: wave does tile t, o-half h ----
    {
        const unsigned short* wAe = (const unsigned short*)smem;
        const unsigned short* Ob  = Obuf + t * 1152;
        short8 B0 = *(const short8*)(Ob + l15 * 72 + q * 8);        // c 0..31
        short8 B1 = *(const short8*)(Ob + l15 * 72 + 32 + q * 8);   // c 32..63
        const float* xw = x   + (size_t)b * Cn * Nn + nw + l15;
        float*       ow = out + (size_t)b * Cn * Nn + nw + l15;
        #pragma unroll
        for (int ot4 = 0; ot4 < 4; ++ot4) {
            const int ot = h * 4 + ot4;
            short8 A0 = *(const short8*)(wAe + (ot * 2 + 0) * 512 + l15 * 32 + q * 8);
            short8 A1 = *(const short8*)(wAe + (ot * 2 + 1) * 512 + l15 * 32 + q * 8);
            floatx4 D = __builtin_amdgcn_mfma_f32_16x16x32_bf16(
                            A0, B0, (floatx4){0.f, 0.f, 0.f, 0.f}, 0, 0, 0);
            D = __builtin_amdgcn_mfma_f32_16x16x32_bf16(A1, B1, D, 0, 0, 0);
            #pragma unroll
            for (int r = 0; r < 4; ++r) {
                int o = ot * 16 + q * 4 + r;
                float v = D[r] + battn[o];
                ow[(size_t)o * Nn] = xw[(size_t)o * Nn] + sg * v;
            }
        }
    }
}

extern "C" void kernel_launch(void* const* d_in, const int* in_sizes, int n_in,
                              void* d_out, int out_size, void* d_ws, size_t ws_size,
                              hipStream_t stream) {
    const float* x       = (const float*)d_in[0];
    const float* w_theta = (const float*)d_in[1];
    const float* b_theta = (const float*)d_in[2];
    const float* w_phi   = (const float*)d_in[3];
    const float* b_phi   = (const float*)d_in[4];
    const float* w_g     = (const float*)d_in[5];
    const float* b_g     = (const float*)d_in[6];
    const float* w_attn  = (const float*)d_in[7];
    const float* b_attn  = (const float*)d_in[8];
    const float* sigma   = (const float*)d_in[9];
    float* out = (float*)d_out;

    unsigned short* thA = (unsigned short*)d_ws;        // 524288 bf16 = 1 MB
    unsigned short* phB = thA + 524288;                 // 131072 bf16 = 256 KB
    unsigned short* gBp = phB + 131072;                 // 524288 bf16 = 1 MB

    k1_pre<<<256, 256, 0, stream>>>(x, w_theta, b_theta, w_phi, b_phi,
                                    w_g, b_g, thA, phB, gBp);
    k2_attn<<<1024, 256, 0, stream>>>(x, thA, phB, gBp, w_attn, b_attn, sigma, out);
}

// Round 10
// 110.301 us; speedup vs baseline: 1.0488x; 1.0488x over previous
//
#include <hip/hip_runtime.h>
#include <hip/hip_bf16.h>
#include <math.h>
#include <string.h>

#define Bn 8
#define Cn 128
#define Nn 4096   // H*W
#define Mn 1024   // N/4
#define C8n 16
#define C2n 64

typedef __attribute__((ext_vector_type(8))) short short8;            // 8 bf16 = 4 VGPRs
typedef __attribute__((ext_vector_type(4))) float floatx4;           // MFMA C/D
typedef __attribute__((ext_vector_type(4))) unsigned short ushortx4; // b64 pack

__device__ __forceinline__ unsigned short f2bf(float f) {
    union { float f; unsigned u; } v; v.f = f;
    unsigned r = v.u + 0x7fff + ((v.u >> 16) & 1);   // RNE
    return (unsigned short)(r >> 16);
}
// packed 2xf32 -> 2xbf16 (v_cvt_pk_bf16_f32 on gfx950)
__device__ __forceinline__ unsigned pk2(float a, float b) {
    __hip_bfloat162 h = __float22bfloat162_rn(make_float2(a, b));
    union { __hip_bfloat162 h2; unsigned u; } cv;
    cv.h2 = h;
    return cv.u;
}

// ---------------------------------------------------------------------------
// K1 (MFMA): unchanged from round 8/9 (proven correct). Outputs:
//  thA[b][nt 256][qd 2][nl 16][dj 8]   (theta * log2e, A-frag order)
//  phB[b][mt 64][qd 2][ml 16][dj 8]    (phi, B-frag order)
//  gB [b][h2 32][cs 4][sq 4][cl 16][sj 8]  (g, B-frag, m permuted s=((m&15)<<1)|(m>>4))
// ---------------------------------------------------------------------------
__global__ __launch_bounds__(256) void k1_pre(
    const float* __restrict__ x,
    const float* __restrict__ w_theta, const float* __restrict__ b_theta,
    const float* __restrict__ w_phi,   const float* __restrict__ b_phi,
    const float* __restrict__ w_g,     const float* __restrict__ b_g,
    unsigned short* __restrict__ thA,
    unsigned short* __restrict__ phB,
    unsigned short* __restrict__ gB)
{
    __shared__ unsigned short wA[6 * 4 * 64 * 8];   // 24 KB [ot][kc][lane][j]
    __shared__ unsigned short xB[8 * 4 * 64 * 8];   // 32 KB [pt][kc][lane][j]
    __shared__ unsigned short pool[80][33];         // 5.2 KB phi rows 0-15, g 16-79
    __shared__ float biases[96];                    // th*L2E 0-15, phi 16-31, g 32-95

    const int t    = threadIdx.x;
    const int b    = blockIdx.x & 7;
    const int h2   = blockIdx.x >> 3;
    const int wv   = t >> 6;
    const int lane = t & 63;
    const int q    = lane >> 4;
    const int l15  = lane & 15;
    const float L2E = 1.4426950408889634f;

    if (t < 96)
        biases[t] = (t < 16) ? b_theta[t] * L2E
                  : (t < 32) ? b_phi[t - 16] : b_g[t - 32];

    #pragma unroll
    for (int k = 0; k < 12; ++k) {
        int u  = t + k * 256;
        int oc = u >> 5, c4 = u & 31;
        const float* src = (oc < 16) ? (w_theta + oc * Cn)
                         : (oc < 32) ? (w_phi + (oc - 16) * Cn)
                                     : (w_g + (oc - 32) * Cn);
        float4 wv4 = *(const float4*)(src + c4 * 4);
        float sc = (oc < 16) ? L2E : 1.f;
        int c = c4 * 4;
        int ot = oc >> 4, kc = c >> 5, qq = (c >> 3) & 3, jj = c & 7;  // jj in {0,4}
        uint2 pk = { pk2(wv4.x * sc, wv4.y * sc), pk2(wv4.z * sc, wv4.w * sc) };
        *(uint2*)(wA + (((ot * 4 + kc) * 64 + qq * 16 + (oc & 15)) * 8 + jj)) = pk;
    }

    const float* xb = x + (size_t)b * Cn * Nn + h2 * 128;
    #pragma unroll
    for (int k = 0; k < 16; ++k) {
        int u   = t + k * 256;
        int pos = u & 127, c4 = u >> 7;
        int c   = c4 * 4;
        float v0 = xb[(size_t)(c + 0) * Nn + pos];
        float v1 = xb[(size_t)(c + 1) * Nn + pos];
        float v2 = xb[(size_t)(c + 2) * Nn + pos];
        float v3 = xb[(size_t)(c + 3) * Nn + pos];
        int pt = pos >> 4, kc = c >> 5, qq = (c >> 3) & 3, jj = c & 7;
        uint2 pk = { pk2(v0, v1), pk2(v2, v3) };
        *(uint2*)(xB + (((pt * 4 + kc) * 64 + qq * 16 + (pos & 15)) * 8 + jj)) = pk;
    }
    __syncthreads();

    floatx4 acc[6][2];
    #pragma unroll
    for (int ot = 0; ot < 6; ++ot)
        #pragma unroll
        for (int p2 = 0; p2 < 2; ++p2) acc[ot][p2] = (floatx4){0.f, 0.f, 0.f, 0.f};

    #pragma unroll
    for (int kc = 0; kc < 4; ++kc) {
        short8 Bf0 = *(const short8*)(xB + ((wv * 4 + kc) * 64 + lane) * 8);
        short8 Bf1 = *(const short8*)(xB + (((wv + 4) * 4 + kc) * 64 + lane) * 8);
        #pragma unroll
        for (int ot = 0; ot < 6; ++ot) {
            short8 Af = *(const short8*)(wA + ((ot * 4 + kc) * 64 + lane) * 8);
            acc[ot][0] = __builtin_amdgcn_mfma_f32_16x16x32_bf16(Af, Bf0, acc[ot][0], 0, 0, 0);
            acc[ot][1] = __builtin_amdgcn_mfma_f32_16x16x32_bf16(Af, Bf1, acc[ot][1], 0, 0, 0);
        }
    }

    #pragma unroll
    for (int p2 = 0; p2 < 2; ++p2) {
        const int pt = wv + p2 * 4;
        float v0 = acc[0][p2][0] + biases[q * 4 + 0];
        float v1 = acc[0][p2][1] + biases[q * 4 + 1];
        float v2 = acc[0][p2][2] + biases[q * 4 + 2];
        float v3 = acc[0][p2][3] + biases[q * 4 + 3];
        uint2 pk = { pk2(v0, v1), pk2(v2, v3) };
        *(uint2*)(thA + ((((size_t)b * 256 + h2 * 8 + pt) * 2 + (q >> 1)) * 128
                         + l15 * 8 + (q & 1) * 4)) = pk;
    }

    #pragma unroll
    for (int ot = 1; ot < 6; ++ot) {
        #pragma unroll
        for (int r = 0; r < 4; ++r) {
            float vmax = fmaxf(acc[ot][0][r], acc[ot][1][r]);
            float pmax = fmaxf(vmax, __shfl_xor(vmax, 1, 64));
            if ((l15 & 1) == 0) {
                int oc = (ot - 1) * 16 + q * 4 + r;      // 0..79
                int w2 = wv * 8 + (l15 >> 1);            // 0..31
                pool[oc][w2] = f2bf(pmax + biases[16 + oc]);
            }
        }
    }
    __syncthreads();

    if (t < 64) {        // phi: units (w2h 2, ml 16, dh 2)
        int w2h = t >> 5, ml = (t >> 1) & 15, dh = t & 1;
        int w2 = w2h * 16 + ml;
        ushortx4 lo, hi;
        #pragma unroll
        for (int j = 0; j < 4; ++j) { lo[j] = pool[dh * 8 + j][w2];
                                      hi[j] = pool[dh * 8 + 4 + j][w2]; }
        unsigned short* dst = phB + (((size_t)b * 64 + h2 * 2 + w2h) * 2 + dh) * 128 + ml * 8;
        *(ushortx4*)dst = lo;
        *(ushortx4*)(dst + 4) = hi;
    }
    {                    // g: units (c 64, sq 4): w2 = (j&1)*16 + sq*4 + (j>>1)
        int c = t >> 2, sq = t & 3;
        ushortx4 lo, hi;
        #pragma unroll
        for (int j = 0; j < 8; ++j) {
            int w2 = (j & 1) * 16 + sq * 4 + (j >> 1);
            unsigned short v = pool[16 + c][w2];
            if (j < 4) lo[j] = v; else hi[j - 4] = v;
        }
        unsigned short* dst = gB + ((((size_t)b * 32 + h2) * 4 + (c >> 4)) * 4 + sq) * 128
                              + (c & 15) * 8;
        *(ushortx4*)dst = lo;
        *(ushortx4*)(dst + 4) = hi;
    }
}

// ---------------------------------------------------------------------------
// K2: MFMA attention + final conv + residual.
// Round-10: NO LDS staging, NO barriers in the main loop. Fragments are
// loaded straight from global (ws layouts are frag-native: one coalesced
// dwordx4 per lane); phi+g is 160 KB/b, L2-hot and shared by the 128 blocks
// with the same b (same XCD via blockIdx&7). Waves free-run over their
// 512-m half in 16 chunks of 32 m; only the wave-private P round-trip uses
// LDS. Partial (O, L) merge across m-halves as in round 9 (pure add).
// LDS 22016 B: Opart/wAe @0 (16 KB) | P 4x1280 @16384 (Obuf overlays) |
// battn @21504.
// ---------------------------------------------------------------------------
__global__ __launch_bounds__(256, 4) void k2_attn(
    const float* __restrict__ x,
    const unsigned short* __restrict__ thA,
    const unsigned short* __restrict__ phB,
    const unsigned short* __restrict__ gB,
    const float* __restrict__ w_attn, const float* __restrict__ b_attn,
    const float* __restrict__ sigma_p,
    float* __restrict__ out)
{
    __shared__ __attribute__((aligned(16))) char smem[22016];
    char*  Pall  = smem + 16384;         // 4 x 1280 B: per-wave P
    float* battn = (float*)(smem + 21504);

    const int tid  = threadIdx.x;
    const int wave = tid >> 6;
    const int lane = tid & 63;
    const int q    = lane >> 4;          // quad 0..3
    const int l15  = lane & 15;
    const int b    = blockIdx.x & 7;     // XCD-local b
    const int nb   = blockIdx.x >> 3;    // 0..127 (32-n block tile)
    const int t    = wave & 1;           // n-tile within block
    const int h    = wave >> 1;          // m-half
    const int ntile = nb * 2 + t;        // global 16-n tile id
    const int nw   = ntile * 16;
    char* Pbase = Pall + wave * 1280;    // [16 n][40 bf16] stride 80 B

    const float sg = sigma_p[0];

    // theta A-frag (quads 2,3 are the K zero-padding)
    short8 thf = {};
    if (q < 2)
        thf = *(const short8*)(thA + ((((size_t)b * 256 + ntile) * 2 + q) * 16 + l15) * 8);

    floatx4 O[4];                        // O[cs] : D[n][c] accumulators
    #pragma unroll
    for (int cs = 0; cs < 4; ++cs) O[cs] = (floatx4){0.f, 0.f, 0.f, 0.f};
    float L[4] = {0.f, 0.f, 0.f, 0.f};

    // this half's fragment sources (global, L2-hot)
    const unsigned short* phh = phB + (size_t)b * 16384 + h * 32 * 256;  // 32 phi tiles
    const unsigned short* ghh = gB  + (size_t)b * 65536 + h * 16 * 2048; // 16 g chunks

    #pragma unroll 2
    for (int s = 0; s < 16; ++s) {
        // ---- fragment loads: 6 coalesced dwordx4, all independent ----
        const unsigned short* pt0 = phh + s * 512;          // 2 tiles of 256
        short8 bf0 = {}, bf1 = {};
        if (q < 2) {
            bf0 = *(const short8*)(pt0 + (q * 16 + l15) * 8);
            bf1 = *(const short8*)(pt0 + 256 + (q * 16 + l15) * 8);
        }
        const unsigned short* gc = ghh + s * 2048;
        short8 Bf0 = *(const short8*)(gc + ((0 * 4 + q) * 16 + l15) * 8);
        short8 Bf1 = *(const short8*)(gc + ((1 * 4 + q) * 16 + l15) * 8);
        short8 Bf2 = *(const short8*)(gc + ((2 * 4 + q) * 16 + l15) * 8);
        short8 Bf3 = *(const short8*)(gc + ((3 * 4 + q) * 16 + l15) * 8);

        // ---- scores (2 m-tiles) -> exp2 -> P (wave-private LDS) ----
        floatx4 S0 = __builtin_amdgcn_mfma_f32_16x16x32_bf16(
                         thf, bf0, (floatx4){0.f, 0.f, 0.f, 0.f}, 0, 0, 0);
        floatx4 S1 = __builtin_amdgcn_mfma_f32_16x16x32_bf16(
                         thf, bf1, (floatx4){0.f, 0.f, 0.f, 0.f}, 0, 0, 0);
        #pragma unroll
        for (int r = 0; r < 4; ++r) {
            float pa = exp2f(S0[r]);
            float pb = exp2f(S1[r]);
            L[r] += pa + pb;
            *(unsigned*)(Pbase + (q * 4 + r) * 80 + l15 * 4) = pk2(pa, pb);
        }
        // no barrier: Pbase is wave-private; same-wave DS ops execute in order

        // ---- PV: one 32-m chunk ----
        short8 Af = *(const short8*)(Pbase + l15 * 80 + q * 16);
        O[0] = __builtin_amdgcn_mfma_f32_16x16x32_bf16(Af, Bf0, O[0], 0, 0, 0);
        O[1] = __builtin_amdgcn_mfma_f32_16x16x32_bf16(Af, Bf1, O[1], 0, 0, 0);
        O[2] = __builtin_amdgcn_mfma_f32_16x16x32_bf16(Af, Bf2, O[2], 0, 0, 0);
        O[3] = __builtin_amdgcn_mfma_f32_16x16x32_bf16(Af, Bf3, O[3], 0, 0, 0);
    }

    // ---- L: sum across the 16 lanes sharing each score row ----
    #pragma unroll
    for (int d = 1; d <= 8; d <<= 1)
        #pragma unroll
        for (int r = 0; r < 4; ++r) L[r] += __shfl_xor(L[r], d, 64);

    // ---- merge m-halves (pure add; no max rescale needed) ----
    __syncthreads();                     // all waves done with main loop
    float* Lpart = (float*)(smem + 8704);        // 2 x 16 floats
    if (h == 1) {                        // write partials: O fp32 [t][n][c], stride 272 B
        #pragma unroll
        for (int r = 0; r < 4; ++r) {
            float* Orow = (float*)(smem + t * 4352 + (q * 4 + r) * 272);
            #pragma unroll
            for (int cs = 0; cs < 4; ++cs) Orow[cs * 16 + l15] = O[cs][r];
            if (l15 == 0) Lpart[t * 16 + q * 4 + r] = L[r];
        }
    }
    if (tid < 128) battn[tid] = b_attn[tid];
    __syncthreads();                     // partials visible
    unsigned short* Obuf = (unsigned short*)(smem + 16384);  // 2 x 1152 shorts, stride 72
    if (h == 0) {                        // merge + normalize + write Obuf bf16
        #pragma unroll
        for (int r = 0; r < 4; ++r) {
            const float* Orow = (const float*)(smem + t * 4352 + (q * 4 + r) * 272);
            #pragma unroll
            for (int cs = 0; cs < 4; ++cs) O[cs][r] += Orow[cs * 16 + l15];
            L[r] += Lpart[t * 16 + q * 4 + r];
        }
        float inv[4];
        #pragma unroll
        for (int r = 0; r < 4; ++r) inv[r] = 1.0f / L[r];
        unsigned short* Ob = Obuf + t * 1152;
        #pragma unroll
        for (int cs = 0; cs < 4; ++cs)
            #pragma unroll
            for (int r = 0; r < 4; ++r)
                Ob[(q * 4 + r) * 72 + cs * 16 + l15] = f2bf(O[cs][r] * inv[r]);
    }
    __syncthreads();                     // Obuf ready; partials dead

    // ---- stage w_attn A-frags [ot 8][kc 2][ol 16][c&31 32] (16 KB @0) ----
    {
        unsigned short* wAe = (unsigned short*)smem;
        #pragma unroll
        for (int k = 0; k < 8; ++k) {
            int i = tid + k * 256;               // 2048 f4 = 128x64 f32
            float4 wv = ((const float4*)w_attn)[i];
            int o = i >> 4, c = (i & 15) * 4;
            uint2 pk = { pk2(wv.x, wv.y), pk2(wv.z, wv.w) };
            *(uint2*)(wAe + ((o >> 4) * 2 + (c >> 5)) * 512 + (o & 15) * 32 + (c & 31)) = pk;
        }
    }
    __syncthreads();                     // wAe visible

    // ---- epilogue conv + residual: wave does tile t, o-half h ----
    {
        const unsigned short* wAe = (const unsigned short*)smem;
        const unsigned short* Ob  = Obuf + t * 1152;
        short8 B0 = *(const short8*)(Ob + l15 * 72 + q * 8);        // c 0..31
        short8 B1 = *(const short8*)(Ob + l15 * 72 + 32 + q * 8);   // c 32..63
        const float* xw = x   + (size_t)b * Cn * Nn + nw + l15;
        float*       ow = out + (size_t)b * Cn * Nn + nw + l15;
        #pragma unroll
        for (int ot4 = 0; ot4 < 4; ++ot4) {
            const int ot = h * 4 + ot4;
            short8 A0 = *(const short8*)(wAe + (ot * 2 + 0) * 512 + l15 * 32 + q * 8);
            short8 A1 = *(const short8*)(wAe + (ot * 2 + 1) * 512 + l15 * 32 + q * 8);
            floatx4 D = __builtin_amdgcn_mfma_f32_16x16x32_bf16(
                            A0, B0, (floatx4){0.f, 0.f, 0.f, 0.f}, 0, 0, 0);
            D = __builtin_amdgcn_mfma_f32_16x16x32_bf16(A1, B1, D, 0, 0, 0);
            #pragma unroll
            for (int r = 0; r < 4; ++r) {
                int o = ot * 16 + q * 4 + r;
                float v = D[r] + battn[o];
                ow[(size_t)o * Nn] = xw[(size_t)o * Nn] + sg * v;
            }
        }
    }
}

extern "C" void kernel_launch(void* const* d_in, const int* in_sizes, int n_in,
                              void* d_out, int out_size, void* d_ws, size_t ws_size,
                              hipStream_t stream) {
    const float* x       = (const float*)d_in[0];
    const float* w_theta = (const float*)d_in[1];
    const float* b_theta = (const float*)d_in[2];
    const float* w_phi   = (const float*)d_in[3];
    const float* b_phi   = (const float*)d_in[4];
    const float* w_g     = (const float*)d_in[5];
    const float* b_g     = (const float*)d_in[6];
    const float* w_attn  = (const float*)d_in[7];
    const float* b_attn  = (const float*)d_in[8];
    const float* sigma   = (const float*)d_in[9];
    float* out = (float*)d_out;

    unsigned short* thA = (unsigned short*)d_ws;        // 524288 bf16 = 1 MB
    unsigned short* phB = thA + 524288;                 // 131072 bf16 = 256 KB
    unsigned short* gBp = phB + 131072;                 // 524288 bf16 = 1 MB

    k1_pre<<<256, 256, 0, stream>>>(x, w_theta, b_theta, w_phi, b_phi,
                                    w_g, b_g, thA, phB, gBp);
    k2_attn<<<1024, 256, 0, stream>>>(x, thA, phB, gBp, w_attn, b_attn, sigma, out);
}

// Round 11
// 109.771 us; speedup vs baseline: 1.0539x; 1.0048x over previous
//
#include <hip/hip_runtime.h>
#include <hip/hip_bf16.h>
#include <math.h>
#include <string.h>

#define Bn 8
#define Cn 128
#define Nn 4096   // H*W
#define Mn 1024   // N/4
#define C8n 16
#define C2n 64

typedef __attribute__((ext_vector_type(8))) short short8;            // 8 bf16 = 4 VGPRs
typedef __attribute__((ext_vector_type(4))) float floatx4;           // MFMA C/D
typedef __attribute__((ext_vector_type(4))) unsigned short ushortx4; // b64 pack

__device__ __forceinline__ unsigned short f2bf(float f) {
    union { float f; unsigned u; } v; v.f = f;
    unsigned r = v.u + 0x7fff + ((v.u >> 16) & 1);   // RNE
    return (unsigned short)(r >> 16);
}
// packed 2xf32 -> 2xbf16 (v_cvt_pk_bf16_f32 on gfx950)
__device__ __forceinline__ unsigned pk2(float a, float b) {
    __hip_bfloat162 h = __float22bfloat162_rn(make_float2(a, b));
    union { __hip_bfloat162 h2; unsigned u; } cv;
    cv.h2 = h;
    return cv.u;
}

// ---------------------------------------------------------------------------
// K1 (MFMA): round-11 = round-10 logic at 512 threads (8 waves -> 2/SIMD).
// Wave w: pt-pair p = w&3 (pos tiles p, p+4), ot-half oh = w>>2 (ots oh*3..+2).
// Outputs (unchanged layouts):
//  thA[b][nt 256][qd 2][nl 16][dj 8]   (theta * log2e, A-frag order)
//  phB[b][mt 64][qd 2][ml 16][dj 8]    (phi, B-frag order)
//  gB [b][h2 32][cs 4][sq 4][cl 16][sj 8]  (g, B-frag, m permuted s=((m&15)<<1)|(m>>4))
// ---------------------------------------------------------------------------
__global__ __launch_bounds__(512) void k1_pre(
    const float* __restrict__ x,
    const float* __restrict__ w_theta, const float* __restrict__ b_theta,
    const float* __restrict__ w_phi,   const float* __restrict__ b_phi,
    const float* __restrict__ w_g,     const float* __restrict__ b_g,
    unsigned short* __restrict__ thA,
    unsigned short* __restrict__ phB,
    unsigned short* __restrict__ gB)
{
    __shared__ unsigned short wA[6 * 4 * 64 * 8];   // 24 KB [ot][kc][lane][j]
    __shared__ unsigned short xB[8 * 4 * 64 * 8];   // 32 KB [pt][kc][lane][j]
    __shared__ unsigned short pool[80][33];         // 5.2 KB phi rows 0-15, g 16-79
    __shared__ float biases[96];                    // th*L2E 0-15, phi 16-31, g 32-95

    const int t    = threadIdx.x;
    const int b    = blockIdx.x & 7;
    const int h2   = blockIdx.x >> 3;
    const int w    = t >> 6;             // 0..7
    const int lane = t & 63;
    const int q    = lane >> 4;
    const int l15  = lane & 15;
    const int p    = w & 3;              // pt-pair
    const int oh   = w >> 2;             // ot-half (ots oh*3 .. oh*3+2)
    const float L2E = 1.4426950408889634f;

    if (t < 96)
        biases[t] = (t < 16) ? b_theta[t] * L2E
                  : (t < 32) ? b_phi[t - 16] : b_g[t - 32];

    // ---- stage weights as bf16 A-frags: 3072 float4 units ----
    #pragma unroll
    for (int k = 0; k < 6; ++k) {
        int u  = t + k * 512;
        int oc = u >> 5, c4 = u & 31;
        const float* src = (oc < 16) ? (w_theta + oc * Cn)
                         : (oc < 32) ? (w_phi + (oc - 16) * Cn)
                                     : (w_g + (oc - 32) * Cn);
        float4 wv4 = *(const float4*)(src + c4 * 4);
        float sc = (oc < 16) ? L2E : 1.f;
        int c = c4 * 4;
        int ot = oc >> 4, kc = c >> 5, qq = (c >> 3) & 3, jj = c & 7;  // jj in {0,4}
        uint2 pk = { pk2(wv4.x * sc, wv4.y * sc), pk2(wv4.z * sc, wv4.w * sc) };
        *(uint2*)(wA + (((ot * 4 + kc) * 64 + qq * 16 + (oc & 15)) * 8 + jj)) = pk;
    }

    // ---- stage x strip as bf16 B-frags: 4096 units ----
    const float* xb = x + (size_t)b * Cn * Nn + h2 * 128;
    #pragma unroll
    for (int k = 0; k < 8; ++k) {
        int u   = t + k * 512;
        int pos = u & 127, c4 = u >> 7;
        int c   = c4 * 4;
        float v0 = xb[(size_t)(c + 0) * Nn + pos];
        float v1 = xb[(size_t)(c + 1) * Nn + pos];
        float v2 = xb[(size_t)(c + 2) * Nn + pos];
        float v3 = xb[(size_t)(c + 3) * Nn + pos];
        int pt = pos >> 4, kc = c >> 5, qq = (c >> 3) & 3, jj = c & 7;
        uint2 pk = { pk2(v0, v1), pk2(v2, v3) };
        *(uint2*)(xB + (((pt * 4 + kc) * 64 + qq * 16 + (pos & 15)) * 8 + jj)) = pk;
    }
    __syncthreads();

    // ---- MFMA: 3 ot x 2 pt x 4 kc = 24 per wave ----
    floatx4 acc[3][2];
    #pragma unroll
    for (int o3 = 0; o3 < 3; ++o3)
        #pragma unroll
        for (int p2 = 0; p2 < 2; ++p2) acc[o3][p2] = (floatx4){0.f, 0.f, 0.f, 0.f};

    #pragma unroll
    for (int kc = 0; kc < 4; ++kc) {
        short8 Bf0 = *(const short8*)(xB + ((p * 4 + kc) * 64 + lane) * 8);
        short8 Bf1 = *(const short8*)(xB + (((p + 4) * 4 + kc) * 64 + lane) * 8);
        #pragma unroll
        for (int o3 = 0; o3 < 3; ++o3) {
            short8 Af = *(const short8*)(wA + (((oh * 3 + o3) * 4 + kc) * 64 + lane) * 8);
            acc[o3][0] = __builtin_amdgcn_mfma_f32_16x16x32_bf16(Af, Bf0, acc[o3][0], 0, 0, 0);
            acc[o3][1] = __builtin_amdgcn_mfma_f32_16x16x32_bf16(Af, Bf1, acc[o3][1], 0, 0, 0);
        }
    }

    // ---- theta (ot==0 lives in oh==0, o3==0): bias + b64 global stores ----
    if (oh == 0) {
        #pragma unroll
        for (int p2 = 0; p2 < 2; ++p2) {
            const int pt = p + p2 * 4;
            float v0 = acc[0][p2][0] + biases[q * 4 + 0];
            float v1 = acc[0][p2][1] + biases[q * 4 + 1];
            float v2 = acc[0][p2][2] + biases[q * 4 + 2];
            float v3 = acc[0][p2][3] + biases[q * 4 + 3];
            uint2 pk = { pk2(v0, v1), pk2(v2, v3) };
            *(uint2*)(thA + ((((size_t)b * 256 + h2 * 8 + pt) * 2 + (q >> 1)) * 128
                             + l15 * 8 + (q & 1) * 4)) = pk;
        }
    }

    // ---- phi/g: 2x2 maxpool in-register, +bias, park in LDS pool ----
    #pragma unroll
    for (int o3 = 0; o3 < 3; ++o3) {
        const int ot = oh * 3 + o3;
        if (ot == 0) continue;
        #pragma unroll
        for (int r = 0; r < 4; ++r) {
            float vmax = fmaxf(acc[o3][0][r], acc[o3][1][r]);
            float pmax = fmaxf(vmax, __shfl_xor(vmax, 1, 64));
            if ((l15 & 1) == 0) {
                int oc = (ot - 1) * 16 + q * 4 + r;      // 0..79
                int w2 = p * 8 + (l15 >> 1);             // 0..31
                pool[oc][w2] = f2bf(pmax + biases[16 + oc]);
            }
        }
    }
    __syncthreads();

    if (t < 64) {        // phi: units (w2h 2, ml 16, dh 2)
        int w2h = t >> 5, ml = (t >> 1) & 15, dh = t & 1;
        int w2 = w2h * 16 + ml;
        ushortx4 lo, hi;
        #pragma unroll
        for (int j = 0; j < 4; ++j) { lo[j] = pool[dh * 8 + j][w2];
                                      hi[j] = pool[dh * 8 + 4 + j][w2]; }
        unsigned short* dst = phB + (((size_t)b * 64 + h2 * 2 + w2h) * 2 + dh) * 128 + ml * 8;
        *(ushortx4*)dst = lo;
        *(ushortx4*)(dst + 4) = hi;
    }
    if (t < 256) {       // g: units (c 64, sq 4): w2 = (j&1)*16 + sq*4 + (j>>1)
        int c = t >> 2, sq = t & 3;
        ushortx4 lo, hi;
        #pragma unroll
        for (int j = 0; j < 8; ++j) {
            int w2 = (j & 1) * 16 + sq * 4 + (j >> 1);
            unsigned short v = pool[16 + c][w2];
            if (j < 4) lo[j] = v; else hi[j - 4] = v;
        }
        unsigned short* dst = gB + ((((size_t)b * 32 + h2) * 4 + (c >> 4)) * 4 + sq) * 128
                              + (c & 15) * 8;
        *(ushortx4*)dst = lo;
        *(ushortx4*)(dst + 4) = hi;
    }
}

// ---------------------------------------------------------------------------
// K2: MFMA attention + final conv + residual.
// Round-11: n-reuse to halve L2 fragment traffic. Block = 4 waves = 4
// m-quarters of one 32-n group; each wave: 32 n (2 theta frags, 8 O accs) x
// 256 m in 8 chunks of 32 m. Fragments straight from global (L2-hot,
// frag-native ws layouts); NO barriers in the main loop; wave-private P.
// 4-way partial merge: all waves write (O,L) partials to LDS, then each wave
// merges 8 rows x 4 copies (lane = channel), normalizes, writes Obuf bf16.
// LDS 38400 B -> 4 blocks/CU (16 waves/CU):
//   P @0 (4x2560, main loop) | partials @0 (4x8192) after loop |
//   Lpart @32768 | Obuf @33280 (4608) | battn @37888 | wAe @0 (16 KB, last).
// ---------------------------------------------------------------------------
__global__ __launch_bounds__(256, 4) void k2_attn(
    const float* __restrict__ x,
    const unsigned short* __restrict__ thA,
    const unsigned short* __restrict__ phB,
    const unsigned short* __restrict__ gB,
    const float* __restrict__ w_attn, const float* __restrict__ b_attn,
    const float* __restrict__ sigma_p,
    float* __restrict__ out)
{
    __shared__ __attribute__((aligned(16))) char smem[38400];
    float* Lpart = (float*)(smem + 32768);          // 4 x 32 floats
    unsigned short* Obuf = (unsigned short*)(smem + 33280); // 2 x 1152 shorts
    float* battn = (float*)(smem + 37888);

    const int tid  = threadIdx.x;
    const int wave = tid >> 6;           // = m-quarter mq
    const int lane = tid & 63;
    const int q    = lane >> 4;          // quad 0..3
    const int l15  = lane & 15;
    const int b    = blockIdx.x & 7;     // XCD-local b
    const int ng   = blockIdx.x >> 3;    // 0..127: 32-n group
    char* Pbase = smem + wave * 2560;    // [t 2][16 n][40 bf16] row stride 80 B

    const float sg = sigma_p[0];

    // theta A-frags for the two 16-n tiles (quads 2,3 = K zero-padding)
    short8 thf[2] = {{}, {}};
    if (q < 2) {
        #pragma unroll
        for (int t = 0; t < 2; ++t)
            thf[t] = *(const short8*)(thA +
                ((((size_t)b * 256 + (ng * 2 + t)) * 2 + q) * 16 + l15) * 8);
    }

    floatx4 O[2][4];                     // O[t][cs] accumulators
    #pragma unroll
    for (int t = 0; t < 2; ++t)
        #pragma unroll
        for (int cs = 0; cs < 4; ++cs) O[t][cs] = (floatx4){0.f, 0.f, 0.f, 0.f};
    float L[2][4] = {{0.f,0.f,0.f,0.f},{0.f,0.f,0.f,0.f}};

    // this m-quarter's fragment sources (global, L2-hot)
    const unsigned short* phh = phB + (size_t)b * 16384 + wave * 4096;   // 16 phi tiles
    const unsigned short* ghh = gB  + (size_t)b * 65536 + wave * 16384;  // 8 g chunks

    #pragma unroll 2
    for (int s = 0; s < 8; ++s) {
        // ---- fragment loads: 6 coalesced dwordx4, all independent ----
        const unsigned short* pt0 = phh + s * 512;          // 2 tiles of 256
        short8 bf0 = {}, bf1 = {};
        if (q < 2) {
            bf0 = *(const short8*)(pt0 + (q * 16 + l15) * 8);
            bf1 = *(const short8*)(pt0 + 256 + (q * 16 + l15) * 8);
        }
        const unsigned short* gc = ghh + s * 2048;
        short8 Bf0 = *(const short8*)(gc + ((0 * 4 + q) * 16 + l15) * 8);
        short8 Bf1 = *(const short8*)(gc + ((1 * 4 + q) * 16 + l15) * 8);
        short8 Bf2 = *(const short8*)(gc + ((2 * 4 + q) * 16 + l15) * 8);
        short8 Bf3 = *(const short8*)(gc + ((3 * 4 + q) * 16 + l15) * 8);

        // ---- scores (2 m-tiles x 2 n-tiles) -> exp2 -> P (wave-private) ----
        #pragma unroll
        for (int t = 0; t < 2; ++t) {
            floatx4 S0 = __builtin_amdgcn_mfma_f32_16x16x32_bf16(
                             thf[t], bf0, (floatx4){0.f, 0.f, 0.f, 0.f}, 0, 0, 0);
            floatx4 S1 = __builtin_amdgcn_mfma_f32_16x16x32_bf16(
                             thf[t], bf1, (floatx4){0.f, 0.f, 0.f, 0.f}, 0, 0, 0);
            #pragma unroll
            for (int r = 0; r < 4; ++r) {
                float pa = exp2f(S0[r]);
                float pb = exp2f(S1[r]);
                L[t][r] += pa + pb;
                *(unsigned*)(Pbase + t * 1280 + (q * 4 + r) * 80 + l15 * 4) = pk2(pa, pb);
            }
        }
        // no barrier: Pbase is wave-private; same-wave DS ops execute in order

        // ---- PV: one 32-m chunk, both n-tiles (g frags reused) ----
        #pragma unroll
        for (int t = 0; t < 2; ++t) {
            short8 Af = *(const short8*)(Pbase + t * 1280 + l15 * 80 + q * 16);
            O[t][0] = __builtin_amdgcn_mfma_f32_16x16x32_bf16(Af, Bf0, O[t][0], 0, 0, 0);
            O[t][1] = __builtin_amdgcn_mfma_f32_16x16x32_bf16(Af, Bf1, O[t][1], 0, 0, 0);
            O[t][2] = __builtin_amdgcn_mfma_f32_16x16x32_bf16(Af, Bf2, O[t][2], 0, 0, 0);
            O[t][3] = __builtin_amdgcn_mfma_f32_16x16x32_bf16(Af, Bf3, O[t][3], 0, 0, 0);
        }
    }

    // ---- L: sum across the 16 lanes sharing each score row ----
    #pragma unroll
    for (int d = 1; d <= 8; d <<= 1)
        #pragma unroll
        for (int t = 0; t < 2; ++t)
            #pragma unroll
            for (int r = 0; r < 4; ++r) L[t][r] += __shfl_xor(L[t][r], d, 64);

    // ---- 4-way partial merge ----
    __syncthreads();                     // main loop done everywhere (P dead)
    {   // all waves write partials: row rho = t*16 + q*4 + r, stride 256 B
        #pragma unroll
        for (int t = 0; t < 2; ++t)
            #pragma unroll
            for (int r = 0; r < 4; ++r) {
                float* row = (float*)(smem + wave * 8192 + (t * 16 + q * 4 + r) * 256);
                #pragma unroll
                for (int cs = 0; cs < 4; ++cs) row[cs * 16 + l15] = O[t][cs][r];
                if (l15 == 0) Lpart[wave * 32 + t * 16 + q * 4 + r] = L[t][r];
            }
    }
    if (tid < 128) battn[tid] = b_attn[tid];
    __syncthreads();                     // partials visible
    {   // wave merges rows wave*8..+7; lane = channel c
        #pragma unroll
        for (int k = 0; k < 8; ++k) {
            const int rho = wave * 8 + k;        // 0..31
            float acc = 0.f, Ls = 0.f;
            #pragma unroll
            for (int w2 = 0; w2 < 4; ++w2) {
                acc += *(const float*)(smem + w2 * 8192 + rho * 256 + lane * 4);
                Ls  += Lpart[w2 * 32 + rho];
            }
            Obuf[(rho >> 4) * 1152 + (rho & 15) * 72 + lane] = f2bf(acc / Ls);
        }
    }
    __syncthreads();                     // Obuf ready; partials dead

    // ---- stage w_attn A-frags [ot 8][kc 2][ol 16][c&31 32] (16 KB @0) ----
    {
        unsigned short* wAe = (unsigned short*)smem;
        #pragma unroll
        for (int k = 0; k < 8; ++k) {
            int i = tid + k * 256;               // 2048 f4 = 128x64 f32
            float4 wv = ((const float4*)w_attn)[i];
            int o = i >> 4, c = (i & 15) * 4;
            uint2 pk = { pk2(wv.x, wv.y), pk2(wv.z, wv.w) };
            *(uint2*)(wAe + ((o >> 4) * 2 + (c >> 5)) * 512 + (o & 15) * 32 + (c & 31)) = pk;
        }
    }
    __syncthreads();                     // wAe visible

    // ---- epilogue conv + residual: wave does tile t=w&1, o-half oh=w>>1 ----
    {
        const int t  = wave & 1;
        const int ohh = wave >> 1;
        const int nw = (ng * 2 + t) * 16;
        const unsigned short* wAe = (const unsigned short*)smem;
        const unsigned short* Ob  = Obuf + t * 1152;
        short8 B0 = *(const short8*)(Ob + l15 * 72 + q * 8);        // c 0..31
        short8 B1 = *(const short8*)(Ob + l15 * 72 + 32 + q * 8);   // c 32..63
        const float* xw = x   + (size_t)b * Cn * Nn + nw + l15;
        float*       ow = out + (size_t)b * Cn * Nn + nw + l15;
        #pragma unroll
        for (int ot4 = 0; ot4 < 4; ++ot4) {
            const int ot = ohh * 4 + ot4;
            short8 A0 = *(const short8*)(wAe + (ot * 2 + 0) * 512 + l15 * 32 + q * 8);
            short8 A1 = *(const short8*)(wAe + (ot * 2 + 1) * 512 + l15 * 32 + q * 8);
            floatx4 D = __builtin_amdgcn_mfma_f32_16x16x32_bf16(
                            A0, B0, (floatx4){0.f, 0.f, 0.f, 0.f}, 0, 0, 0);
            D = __builtin_amdgcn_mfma_f32_16x16x32_bf16(A1, B1, D, 0, 0, 0);
            #pragma unroll
            for (int r = 0; r < 4; ++r) {
                int o = ot * 16 + q * 4 + r;
                float v = D[r] + battn[o];
                ow[(size_t)o * Nn] = xw[(size_t)o * Nn] + sg * v;
            }
        }
    }
}

extern "C" void kernel_launch(void* const* d_in, const int* in_sizes, int n_in,
                              void* d_out, int out_size, void* d_ws, size_t ws_size,
                              hipStream_t stream) {
    const float* x       = (const float*)d_in[0];
    const float* w_theta = (const float*)d_in[1];
    const float* b_theta = (const float*)d_in[2];
    const float* w_phi   = (const float*)d_in[3];
    const float* b_phi   = (const float*)d_in[4];
    const float* w_g     = (const float*)d_in[5];
    const float* b_g     = (const float*)d_in[6];
    const float* w_attn  = (const float*)d_in[7];
    const float* b_attn  = (const float*)d_in[8];
    const float* sigma   = (const float*)d_in[9];
    float* out = (float*)d_out;

    unsigned short* thA = (unsigned short*)d_ws;        // 524288 bf16 = 1 MB
    unsigned short* phB = thA + 524288;                 // 131072 bf16 = 256 KB
    unsigned short* gBp = phB + 131072;                 // 524288 bf16 = 1 MB

    k1_pre<<<256, 512, 0, stream>>>(x, w_theta, b_theta, w_phi, b_phi,
                                    w_g, b_g, thA, phB, gBp);
    k2_attn<<<1024, 256, 0, stream>>>(x, thA, phB, gBp, w_attn, b_attn, sigma, out);
}

// Round 12
// 108.648 us; speedup vs baseline: 1.0648x; 1.0103x over previous
//
#include <hip/hip_runtime.h>
#include <hip/hip_bf16.h>
#include <math.h>
#include <string.h>

#define Bn 8
#define Cn 128
#define Nn 4096   // H*W
#define Mn 1024   // N/4
#define C8n 16
#define C2n 64

typedef __attribute__((ext_vector_type(8))) short short8;            // 8 bf16 = 4 VGPRs
typedef __attribute__((ext_vector_type(4))) float floatx4;           // MFMA C/D
typedef __attribute__((ext_vector_type(4))) unsigned short ushortx4; // b64 pack

__device__ __forceinline__ unsigned short f2bf(float f) {
    union { float f; unsigned u; } v; v.f = f;
    unsigned r = v.u + 0x7fff + ((v.u >> 16) & 1);   // RNE
    return (unsigned short)(r >> 16);
}
// packed 2xf32 -> 2xbf16 (v_cvt_pk_bf16_f32 on gfx950)
__device__ __forceinline__ unsigned pk2(float a, float b) {
    __hip_bfloat162 h = __float22bfloat162_rn(make_float2(a, b));
    union { __hip_bfloat162 h2; unsigned u; } cv;
    cv.h2 = h;
    return cv.u;
}

// ---------------------------------------------------------------------------
// K1 (MFMA), round-12: oc-split across 512 blocks -> 2 blocks/CU so one
// block's MFMA phase overlaps the other's staging stalls.
// Block = (half, h2, b): computes oc range [half*48, half*48+48) for the
// 2-row strip. half0 = theta(16) + phi(16) + g[0..15]; half1 = g[16..63].
// 256 threads = 4 waves; wave w owns pos-tile pair {w, w+4}, all 3 oc-tiles.
// Output layouts unchanged:
//  thA[b][nt 256][qd 2][nl 16][dj 8]   (theta * log2e, A-frag order)
//  phB[b][mt 64][qd 2][ml 16][dj 8]    (phi, B-frag order)
//  gB [b][h2 32][cs 4][sq 4][cl 16][sj 8]  (g, B-frag, m permuted s=((m&15)<<1)|(m>>4))
// ---------------------------------------------------------------------------
__global__ __launch_bounds__(256) void k1_pre(
    const float* __restrict__ x,
    const float* __restrict__ w_theta, const float* __restrict__ b_theta,
    const float* __restrict__ w_phi,   const float* __restrict__ b_phi,
    const float* __restrict__ w_g,     const float* __restrict__ b_g,
    unsigned short* __restrict__ thA,
    unsigned short* __restrict__ phB,
    unsigned short* __restrict__ gB)
{
    __shared__ unsigned short wA[3 * 4 * 64 * 8];   // 12 KB [ot_l][kc][lane][j]
    __shared__ unsigned short xB[8 * 4 * 64 * 8];   // 32 KB [pt][kc][lane][j]
    __shared__ unsigned short pool[48][33];         // 3.2 KB (local rows)
    __shared__ float biases[96];                    // th*L2E 0-15, phi 16-31, g 32-95

    const int t    = threadIdx.x;
    const int b    = blockIdx.x & 7;
    const int h2   = (blockIdx.x >> 3) & 31;
    const int half = blockIdx.x >> 8;    // 0 or 1
    const int w    = t >> 6;             // 0..3: pt-pair
    const int lane = t & 63;
    const int q    = lane >> 4;
    const int l15  = lane & 15;
    const float L2E = 1.4426950408889634f;

    if (t < 96)
        biases[t] = (t < 16) ? b_theta[t] * L2E
                  : (t < 32) ? b_phi[t - 16] : b_g[t - 32];

    // ---- stage this half's weights as bf16 A-frags: 48 oc x 32 f4 = 1536 ----
    #pragma unroll
    for (int k = 0; k < 6; ++k) {
        int u   = t + k * 256;
        int loc = u >> 5, c4 = u & 31;          // local oc 0..47
        int ocg = half * 48 + loc;              // global oc 0..95
        const float* src = (ocg < 16) ? (w_theta + ocg * Cn)
                         : (ocg < 32) ? (w_phi + (ocg - 16) * Cn)
                                      : (w_g + (ocg - 32) * Cn);
        float4 wv4 = *(const float4*)(src + c4 * 4);
        float sc = (ocg < 16) ? L2E : 1.f;
        int c = c4 * 4;
        int ot = loc >> 4, kc = c >> 5, qq = (c >> 3) & 3, jj = c & 7;  // jj in {0,4}
        uint2 pk = { pk2(wv4.x * sc, wv4.y * sc), pk2(wv4.z * sc, wv4.w * sc) };
        *(uint2*)(wA + (((ot * 4 + kc) * 64 + qq * 16 + (loc & 15)) * 8 + jj)) = pk;
    }

    // ---- stage x strip as bf16 B-frags: 4096 units ----
    const float* xb = x + (size_t)b * Cn * Nn + h2 * 128;
    #pragma unroll
    for (int k = 0; k < 16; ++k) {
        int u   = t + k * 256;
        int pos = u & 127, c4 = u >> 7;
        int c   = c4 * 4;
        float v0 = xb[(size_t)(c + 0) * Nn + pos];
        float v1 = xb[(size_t)(c + 1) * Nn + pos];
        float v2 = xb[(size_t)(c + 2) * Nn + pos];
        float v3 = xb[(size_t)(c + 3) * Nn + pos];
        int pt = pos >> 4, kc = c >> 5, qq = (c >> 3) & 3, jj = c & 7;
        uint2 pk = { pk2(v0, v1), pk2(v2, v3) };
        *(uint2*)(xB + (((pt * 4 + kc) * 64 + qq * 16 + (pos & 15)) * 8 + jj)) = pk;
    }
    __syncthreads();

    // ---- MFMA: 3 ot x 2 pt x 4 kc = 24 per wave ----
    floatx4 acc[3][2];
    #pragma unroll
    for (int o3 = 0; o3 < 3; ++o3)
        #pragma unroll
        for (int p2 = 0; p2 < 2; ++p2) acc[o3][p2] = (floatx4){0.f, 0.f, 0.f, 0.f};

    #pragma unroll
    for (int kc = 0; kc < 4; ++kc) {
        short8 Bf0 = *(const short8*)(xB + ((w * 4 + kc) * 64 + lane) * 8);
        short8 Bf1 = *(const short8*)(xB + (((w + 4) * 4 + kc) * 64 + lane) * 8);
        #pragma unroll
        for (int o3 = 0; o3 < 3; ++o3) {
            short8 Af = *(const short8*)(wA + ((o3 * 4 + kc) * 64 + lane) * 8);
            acc[o3][0] = __builtin_amdgcn_mfma_f32_16x16x32_bf16(Af, Bf0, acc[o3][0], 0, 0, 0);
            acc[o3][1] = __builtin_amdgcn_mfma_f32_16x16x32_bf16(Af, Bf1, acc[o3][1], 0, 0, 0);
        }
    }

    // ---- theta (half0, o3==0): bias + b64 global stores ----
    if (half == 0) {
        #pragma unroll
        for (int p2 = 0; p2 < 2; ++p2) {
            const int pt = w + p2 * 4;
            float v0 = acc[0][p2][0] + biases[q * 4 + 0];
            float v1 = acc[0][p2][1] + biases[q * 4 + 1];
            float v2 = acc[0][p2][2] + biases[q * 4 + 2];
            float v3 = acc[0][p2][3] + biases[q * 4 + 3];
            uint2 pk = { pk2(v0, v1), pk2(v2, v3) };
            *(uint2*)(thA + ((((size_t)b * 256 + h2 * 8 + pt) * 2 + (q >> 1)) * 128
                             + l15 * 8 + (q & 1) * 4)) = pk;
        }
    }

    // ---- phi/g: 2x2 maxpool in-register, +bias, park in LDS pool ----
    #pragma unroll
    for (int o3 = 0; o3 < 3; ++o3) {
        const int ocg = half * 48 + o3 * 16;     // tile's global oc base
        if (ocg == 0) continue;                  // theta tile handled above
        #pragma unroll
        for (int r = 0; r < 4; ++r) {
            float vmax = fmaxf(acc[o3][0][r], acc[o3][1][r]);
            float pmax = fmaxf(vmax, __shfl_xor(vmax, 1, 64));
            if ((l15 & 1) == 0) {
                int oc = ocg + q * 4 + r;                // global oc 16..95
                int prow = (half == 0) ? (oc - 16)       // phi 0..15, g0..15 -> 16..31
                                       : (oc - 48);      // g16..63 -> rows 0..47
                int w2 = w * 8 + (l15 >> 1);             // 0..31
                pool[prow][w2] = f2bf(pmax + biases[16 + (oc - 16) + ((oc >= 32) ? 16 : 0)]);
            }
        }
    }
    __syncthreads();

    if (half == 0) {
        if (t < 64) {    // phi: units (w2h 2, ml 16, dh 2), pool rows 0..15
            int w2h = t >> 5, ml = (t >> 1) & 15, dh = t & 1;
            int w2 = w2h * 16 + ml;
            ushortx4 lo, hi;
            #pragma unroll
            for (int j = 0; j < 4; ++j) { lo[j] = pool[dh * 8 + j][w2];
                                          hi[j] = pool[dh * 8 + 4 + j][w2]; }
            unsigned short* dst = phB + (((size_t)b * 64 + h2 * 2 + w2h) * 2 + dh) * 128 + ml * 8;
            *(ushortx4*)dst = lo;
            *(ushortx4*)(dst + 4) = hi;
        } else if (t < 128) {  // g c 0..15 (pool rows 16..31): 64 units
            int u = t - 64;
            int c = u >> 2, sq = u & 3;          // c 0..15
            ushortx4 lo, hi;
            #pragma unroll
            for (int j = 0; j < 8; ++j) {
                int w2 = (j & 1) * 16 + sq * 4 + (j >> 1);
                unsigned short v = pool[16 + c][w2];
                if (j < 4) lo[j] = v; else hi[j - 4] = v;
            }
            unsigned short* dst = gB + ((((size_t)b * 32 + h2) * 4 + (c >> 4)) * 4 + sq) * 128
                                  + (c & 15) * 8;
            *(ushortx4*)dst = lo;
            *(ushortx4*)(dst + 4) = hi;
        }
    } else {
        if (t < 192) {   // g c 16..63 (pool rows 0..47): 192 units
            int cl = t >> 2, sq = t & 3;         // cl 0..47
            int c  = 16 + cl;
            ushortx4 lo, hi;
            #pragma unroll
            for (int j = 0; j < 8; ++j) {
                int w2 = (j & 1) * 16 + sq * 4 + (j >> 1);
                unsigned short v = pool[cl][w2];
                if (j < 4) lo[j] = v; else hi[j - 4] = v;
            }
            unsigned short* dst = gB + ((((size_t)b * 32 + h2) * 4 + (c >> 4)) * 4 + sq) * 128
                                  + (c & 15) * 8;
            *(ushortx4*)dst = lo;
            *(ushortx4*)(dst + 4) = hi;
        }
    }
}

// ---------------------------------------------------------------------------
// K2: MFMA attention + final conv + residual. UNCHANGED from round 11.
// Block = 4 waves = 4 m-quarters of one 32-n group; each wave: 32 n x 256 m.
// Fragments straight from global (L2-hot frag-native ws layouts); no barriers
// in the main loop; wave-private P; 4-way partial merge; MFMA epilogue.
// ---------------------------------------------------------------------------
__global__ __launch_bounds__(256, 4) void k2_attn(
    const float* __restrict__ x,
    const unsigned short* __restrict__ thA,
    const unsigned short* __restrict__ phB,
    const unsigned short* __restrict__ gB,
    const float* __restrict__ w_attn, const float* __restrict__ b_attn,
    const float* __restrict__ sigma_p,
    float* __restrict__ out)
{
    __shared__ __attribute__((aligned(16))) char smem[38400];
    float* Lpart = (float*)(smem + 32768);          // 4 x 32 floats
    unsigned short* Obuf = (unsigned short*)(smem + 33280); // 2 x 1152 shorts
    float* battn = (float*)(smem + 37888);

    const int tid  = threadIdx.x;
    const int wave = tid >> 6;           // = m-quarter
    const int lane = tid & 63;
    const int q    = lane >> 4;          // quad 0..3
    const int l15  = lane & 15;
    const int b    = blockIdx.x & 7;     // XCD-local b
    const int ng   = blockIdx.x >> 3;    // 0..127: 32-n group
    char* Pbase = smem + wave * 2560;    // [t 2][16 n][40 bf16] row stride 80 B

    const float sg = sigma_p[0];

    // theta A-frags for the two 16-n tiles (quads 2,3 = K zero-padding)
    short8 thf[2] = {{}, {}};
    if (q < 2) {
        #pragma unroll
        for (int t = 0; t < 2; ++t)
            thf[t] = *(const short8*)(thA +
                ((((size_t)b * 256 + (ng * 2 + t)) * 2 + q) * 16 + l15) * 8);
    }

    floatx4 O[2][4];                     // O[t][cs] accumulators
    #pragma unroll
    for (int t = 0; t < 2; ++t)
        #pragma unroll
        for (int cs = 0; cs < 4; ++cs) O[t][cs] = (floatx4){0.f, 0.f, 0.f, 0.f};
    float L[2][4] = {{0.f,0.f,0.f,0.f},{0.f,0.f,0.f,0.f}};

    // this m-quarter's fragment sources (global, L2-hot)
    const unsigned short* phh = phB + (size_t)b * 16384 + wave * 4096;   // 16 phi tiles
    const unsigned short* ghh = gB  + (size_t)b * 65536 + wave * 16384;  // 8 g chunks

    #pragma unroll 2
    for (int s = 0; s < 8; ++s) {
        // ---- fragment loads: 6 coalesced dwordx4, all independent ----
        const unsigned short* pt0 = phh + s * 512;          // 2 tiles of 256
        short8 bf0 = {}, bf1 = {};
        if (q < 2) {
            bf0 = *(const short8*)(pt0 + (q * 16 + l15) * 8);
            bf1 = *(const short8*)(pt0 + 256 + (q * 16 + l15) * 8);
        }
        const unsigned short* gc = ghh + s * 2048;
        short8 Bf0 = *(const short8*)(gc + ((0 * 4 + q) * 16 + l15) * 8);
        short8 Bf1 = *(const short8*)(gc + ((1 * 4 + q) * 16 + l15) * 8);
        short8 Bf2 = *(const short8*)(gc + ((2 * 4 + q) * 16 + l15) * 8);
        short8 Bf3 = *(const short8*)(gc + ((3 * 4 + q) * 16 + l15) * 8);

        // ---- scores (2 m-tiles x 2 n-tiles) -> exp2 -> P (wave-private) ----
        #pragma unroll
        for (int t = 0; t < 2; ++t) {
            floatx4 S0 = __builtin_amdgcn_mfma_f32_16x16x32_bf16(
                             thf[t], bf0, (floatx4){0.f, 0.f, 0.f, 0.f}, 0, 0, 0);
            floatx4 S1 = __builtin_amdgcn_mfma_f32_16x16x32_bf16(
                             thf[t], bf1, (floatx4){0.f, 0.f, 0.f, 0.f}, 0, 0, 0);
            #pragma unroll
            for (int r = 0; r < 4; ++r) {
                float pa = exp2f(S0[r]);
                float pb = exp2f(S1[r]);
                L[t][r] += pa + pb;
                *(unsigned*)(Pbase + t * 1280 + (q * 4 + r) * 80 + l15 * 4) = pk2(pa, pb);
            }
        }
        // no barrier: Pbase is wave-private; same-wave DS ops execute in order

        // ---- PV: one 32-m chunk, both n-tiles (g frags reused) ----
        #pragma unroll
        for (int t = 0; t < 2; ++t) {
            short8 Af = *(const short8*)(Pbase + t * 1280 + l15 * 80 + q * 16);
            O[t][0] = __builtin_amdgcn_mfma_f32_16x16x32_bf16(Af, Bf0, O[t][0], 0, 0, 0);
            O[t][1] = __builtin_amdgcn_mfma_f32_16x16x32_bf16(Af, Bf1, O[t][1], 0, 0, 0);
            O[t][2] = __builtin_amdgcn_mfma_f32_16x16x32_bf16(Af, Bf2, O[t][2], 0, 0, 0);
            O[t][3] = __builtin_amdgcn_mfma_f32_16x16x32_bf16(Af, Bf3, O[t][3], 0, 0, 0);
        }
    }

    // ---- L: sum across the 16 lanes sharing each score row ----
    #pragma unroll
    for (int d = 1; d <= 8; d <<= 1)
        #pragma unroll
        for (int t = 0; t < 2; ++t)
            #pragma unroll
            for (int r = 0; r < 4; ++r) L[t][r] += __shfl_xor(L[t][r], d, 64);

    // ---- 4-way partial merge ----
    __syncthreads();                     // main loop done everywhere (P dead)
    {   // all waves write partials: row rho = t*16 + q*4 + r, stride 256 B
        #pragma unroll
        for (int t = 0; t < 2; ++t)
            #pragma unroll
            for (int r = 0; r < 4; ++r) {
                float* row = (float*)(smem + wave * 8192 + (t * 16 + q * 4 + r) * 256);
                #pragma unroll
                for (int cs = 0; cs < 4; ++cs) row[cs * 16 + l15] = O[t][cs][r];
                if (l15 == 0) Lpart[wave * 32 + t * 16 + q * 4 + r] = L[t][r];
            }
    }
    if (tid < 128) battn[tid] = b_attn[tid];
    __syncthreads();                     // partials visible
    {   // wave merges rows wave*8..+7; lane = channel c
        #pragma unroll
        for (int k = 0; k < 8; ++k) {
            const int rho = wave * 8 + k;        // 0..31
            float acc = 0.f, Ls = 0.f;
            #pragma unroll
            for (int w2 = 0; w2 < 4; ++w2) {
                acc += *(const float*)(smem + w2 * 8192 + rho * 256 + lane * 4);
                Ls  += Lpart[w2 * 32 + rho];
            }
            Obuf[(rho >> 4) * 1152 + (rho & 15) * 72 + lane] = f2bf(acc / Ls);
        }
    }
    __syncthreads();                     // Obuf ready; partials dead

    // ---- stage w_attn A-frags [ot 8][kc 2][ol 16][c&31 32] (16 KB @0) ----
    {
        unsigned short* wAe = (unsigned short*)smem;
        #pragma unroll
        for (int k = 0; k < 8; ++k) {
            int i = tid + k * 256;               // 2048 f4 = 128x64 f32
            float4 wv = ((const float4*)w_attn)[i];
            int o = i >> 4, c = (i & 15) * 4;
            uint2 pk = { pk2(wv.x, wv.y), pk2(wv.z, wv.w) };
            *(uint2*)(wAe + ((o >> 4) * 2 + (c >> 5)) * 512 + (o & 15) * 32 + (c & 31)) = pk;
        }
    }
    __syncthreads();                     // wAe visible

    // ---- epilogue conv + residual: wave does tile t=w&1, o-half oh=w>>1 ----
    {
        const int t  = wave & 1;
        const int ohh = wave >> 1;
        const int nw = (ng * 2 + t) * 16;
        const unsigned short* wAe = (const unsigned short*)smem;
        const unsigned short* Ob  = Obuf + t * 1152;
        short8 B0 = *(const short8*)(Ob + l15 * 72 + q * 8);        // c 0..31
        short8 B1 = *(const short8*)(Ob + l15 * 72 + 32 + q * 8);   // c 32..63
        const float* xw = x   + (size_t)b * Cn * Nn + nw + l15;
        float*       ow = out + (size_t)b * Cn * Nn + nw + l15;
        #pragma unroll
        for (int ot4 = 0; ot4 < 4; ++ot4) {
            const int ot = ohh * 4 + ot4;
            short8 A0 = *(const short8*)(wAe + (ot * 2 + 0) * 512 + l15 * 32 + q * 8);
            short8 A1 = *(const short8*)(wAe + (ot * 2 + 1) * 512 + l15 * 32 + q * 8);
            floatx4 D = __builtin_amdgcn_mfma_f32_16x16x32_bf16(
                            A0, B0, (floatx4){0.f, 0.f, 0.f, 0.f}, 0, 0, 0);
            D = __builtin_amdgcn_mfma_f32_16x16x32_bf16(A1, B1, D, 0, 0, 0);
            #pragma unroll
            for (int r = 0; r < 4; ++r) {
                int o = ot * 16 + q * 4 + r;
                float v = D[r] + battn[o];
                ow[(size_t)o * Nn] = xw[(size_t)o * Nn] + sg * v;
            }
        }
    }
}

extern "C" void kernel_launch(void* const* d_in, const int* in_sizes, int n_in,
                              void* d_out, int out_size, void* d_ws, size_t ws_size,
                              hipStream_t stream) {
    const float* x       = (const float*)d_in[0];
    const float* w_theta = (const float*)d_in[1];
    const float* b_theta = (const float*)d_in[2];
    const float* w_phi   = (const float*)d_in[3];
    const float* b_phi   = (const float*)d_in[4];
    const float* w_g     = (const float*)d_in[5];
    const float* b_g     = (const float*)d_in[6];
    const float* w_attn  = (const float*)d_in[7];
    const float* b_attn  = (const float*)d_in[8];
    const float* sigma   = (const float*)d_in[9];
    float* out = (float*)d_out;

    unsigned short* thA = (unsigned short*)d_ws;        // 524288 bf16 = 1 MB
    unsigned short* phB = thA + 524288;                 // 131072 bf16 = 256 KB
    unsigned short* gBp = phB + 131072;                 // 524288 bf16 = 1 MB

    k1_pre<<<512, 256, 0, stream>>>(x, w_theta, b_theta, w_phi, b_phi,
                                    w_g, b_g, thA, phB, gBp);
    k2_attn<<<1024, 256, 0, stream>>>(x, thA, phB, gBp, w_attn, b_attn, sigma, out);
}